// Round 1
// baseline (74.800 us; speedup 1.0000x reference)
//
#include <hip/hip_runtime.h>
#include <math.h>

#define W_IMG 512
#define H_IMG 512
#define ALPHA_MIN (1.0f/255.0f)
#define ALPHA_MAX 0.999f
#define CHUNK 256

// Single fused kernel: per-gaussian parameter computation happens per-block,
// per-chunk, in registers (no workspace, no second dispatch). The per-block
// redundancy is ~2048 gaussians x ~40 VALU ops x 1024 blocks ~= 1 us total --
// negligible vs. the dispatch + 256 MiB workspace re-poison it eliminates.
//
// Cull: gaussian is invisible on this tile if min over tile pixels of sigma
// exceeds T = ln(255*op). Exact lower bounds (Cauchy-Schwarz on the PD
// covariance C = [[a,b],[b,c]], eigenvalues s0,s1):
//   sigma >= ddx^2/(2a), sigma >= ddy^2/(2c), sigma >= (ddx^2+ddy^2)/(2*max(s0,s1))
// where (ddx,ddy) is the rect-distance from the tile to the center. Cull if
// any bound already exceeds T (with the same conservative margin style the
// previous passing kernel used).
__global__ __launch_bounds__(256) void splat_fused(
    const float* __restrict__ xyz,
    const float* __restrict__ scaling,
    const float* __restrict__ rotation,
    const float* __restrict__ features,
    const float* __restrict__ opacity,
    float* __restrict__ out, int N)
{
  __shared__ float4 sA[CHUNK];   // mx, my, h0=0.5*c0, h1=c1
  __shared__ float4 sB[CHUNK];   // h2=0.5*c2, f0, f1, f2
  __shared__ float  sOp[CHUNK];
  __shared__ int wcnt[4];

  const int tid = threadIdx.x;
  const int tile_x = blockIdx.x << 4;
  const int tile_y = blockIdx.y << 4;
  const int lx = tid & 15, ly = tid >> 4;
  const float px = (float)(tile_x + lx);
  const float py = (float)(tile_y + ly);
  const float tx0 = (float)tile_x, tx1 = (float)(tile_x + 15);
  const float ty0 = (float)tile_y, ty1 = (float)(tile_y + 15);

  float acc0 = 0.f, acc1 = 0.f, acc2 = 0.f;

  for (int base = 0; base < N; base += CHUNK) {
    const int gi = base + tid;
    bool keep = false;
    float mx = 0.f, my = 0.f, h0 = 0.f, h1 = 0.f, h2 = 0.f, op = 0.f;
    float f0 = 0.f, f1 = 0.f, f2 = 0.f;
    if (gi < N) {
      const float2 xy = ((const float2*)xyz)[gi];
      const float2 sc = ((const float2*)scaling)[gi];
      const float rot = rotation[gi];
      op = opacity[gi];
      const float theta = 6.28318530717958647692f / (1.0f + __expf(-rot));
      float sn, cs;
      __sincosf(theta, &sn, &cs);
      const float sxa = fabsf(sc.x), sya = fabsf(sc.y);
      const float s0 = sxa*sxa, s1 = sya*sya;
      const float a = cs*cs*s0 + sn*sn*s1;       // cov xx
      const float b = cs*sn*(s0 - s1);           // cov xy
      const float c = sn*sn*s0 + cs*cs*s1;       // cov yy
      const float inv_det = 1.0f / (a*c - b*b);
      h0 = 0.5f * c * inv_det;
      h1 = -b * inv_det;
      h2 = 0.5f * a * inv_det;
      mx = 0.5f*((xy.x + 1.0f)*(float)W_IMG - 1.0f);
      my = 0.5f*((xy.y + 1.0f)*(float)H_IMG - 1.0f);
      if (op > 0.0f) {
        const float T = __logf(255.0f * op);
        if (T > 0.0f) {
          const float T2 = 2.0f * T * 1.0005f;
          const float rx2 = fmaf(T2, a, 0.05f);                // box bound x
          const float ry2 = fmaf(T2, c, 0.05f);                // box bound y
          const float rc2 = fmaf(T2, fmaxf(s0, s1), 0.05f);    // circle bound
          const float ddx = fmaxf(fmaxf(tx0 - mx, mx - tx1), 0.0f);
          const float ddy = fmaxf(fmaxf(ty0 - my, my - ty1), 0.0f);
          const float dx2 = ddx*ddx, dy2 = ddy*ddy;
          keep = (dx2 <= rx2) && (dy2 <= ry2) && (dx2 + dy2 <= rc2);
        }
      }
      if (keep) {
        f0 = features[3*gi+0];
        f1 = features[3*gi+1];
        f2 = features[3*gi+2];
      }
    }

    // ballot-compact survivors into LDS (deterministic order)
    const unsigned long long m = __ballot(keep);
    const int lane = tid & 63, wid = tid >> 6;
    const int pre = __popcll(m & ((1ull << lane) - 1ull));
    if (lane == 0) wcnt[wid] = __popcll(m);
    __syncthreads();
    int wbase = 0, total = 0;
    #pragma unroll
    for (int w = 0; w < 4; ++w) { const int cw = wcnt[w]; if (w < wid) wbase += cw; total += cw; }
    if (keep) {
      const int p = wbase + pre;
      sA[p] = make_float4(mx, my, h0, h1);
      sB[p] = make_float4(h2, f0, f1, f2);
      sOp[p] = op;
    }
    __syncthreads();

    for (int j = 0; j < total; ++j) {
      const float4 gA = sA[j];
      const float4 gB = sB[j];
      const float opj = sOp[j];
      const float dx = px - gA.x;
      const float dy = py - gA.y;
      const float sig = fmaf(dx, fmaf(gA.z, dx, gA.w*dy), gB.x*dy*dy);
      const float e = __expf(-sig);
      float alpha = fminf(ALPHA_MAX, opj * e);
      alpha = (alpha < ALPHA_MIN) ? 0.0f : alpha;
      acc0 = fmaf(alpha, gB.y, acc0);
      acc1 = fmaf(alpha, gB.z, acc1);
      acc2 = fmaf(alpha, gB.w, acc2);
    }
    __syncthreads();   // protect wcnt/sA before next chunk overwrites
  }

  const int x = tile_x + lx, y = tile_y + ly;
  const int pix = y * W_IMG + x;
  out[pix]                 = fminf(fmaxf(acc0, 0.0f), 1.0f);
  out[W_IMG*H_IMG + pix]   = fminf(fmaxf(acc1, 0.0f), 1.0f);
  out[2*W_IMG*H_IMG + pix] = fminf(fmaxf(acc2, 0.0f), 1.0f);
}

extern "C" void kernel_launch(void* const* d_in, const int* in_sizes, int n_in,
                              void* d_out, int out_size, void* d_ws, size_t ws_size,
                              hipStream_t stream) {
  const float* xyz      = (const float*)d_in[0];
  const float* scaling  = (const float*)d_in[1];
  const float* rotation = (const float*)d_in[2];
  const float* features = (const float*)d_in[3];
  const float* opacity  = (const float*)d_in[4];
  float* out = (float*)d_out;
  const int N = in_sizes[0] / 2;

  (void)d_ws; (void)ws_size;  // workspace intentionally unused

  dim3 grid(W_IMG / 16, H_IMG / 16);
  splat_fused<<<grid, 256, 0, stream>>>(xyz, scaling, rotation, features,
                                        opacity, out, N);
}